// Round 14
// baseline (73.383 us; speedup 1.0000x reference)
//
#include <hip/hip_runtime.h>

#define IMG  4096
#define H    8               // output rows per wave strip
#define W103 3.33333333333333f   // 10/3 (x3 scharr scale deferred to epilogue)

typedef float f32x4 __attribute__((ext_vector_type(4)));

__global__ __launch_bounds__(256)
void harris_stream8(const float* __restrict__ x,
                    float* __restrict__ out_edge,
                    float* __restrict__ out_eig)
{
    const int lane  = threadIdx.x;                    // 0..63
    const int panel = blockIdx.x * 4 + threadIdx.y;   // 0..15 (256 cols each)
    const int r0    = blockIdx.y * H;
    const int cb    = panel * 256 + lane * 4;         // output col base (mult of 4)
    const bool eL   = (cb == 0);
    const bool eR   = (cb == IMG - 4);
    const int  cA   = eL ? 0 : cb - 2;                // LA: gray cols cA..cA+3 (8B aligned)
    const int  cB   = eR ? cb : cb + 2;               // LB: gray cols cB..cB+3

    const float* __restrict__ x0 = x;
    const float* __restrict__ x1 = x + (size_t)IMG * IMG;
    const float* __restrict__ x2 = x + 2 * (size_t)IMG * IMG;

    auto rowbase = [&](int r) -> int {                // clamped, always-safe row base
        int rc = min(max(r, 0), IMG - 1);
        return rc * IMG;
    };

    float ga[8], gb[8], gc[8];                        // gray ring rows e-1, e, e+1

    // build gray[8] = cols cb-2..cb+5 (edge-adjusted, zero outside image)
    auto mk8 = [&](f32x4 A0, f32x4 A1, f32x4 A2,
                   f32x4 B0, f32x4 B1, f32x4 B2, int r, float* g) {
        f32x4 GA = 0.299f * A0 + 0.587f * A1 + 0.114f * A2;
        f32x4 GB = 0.299f * B0 + 0.587f * B1 + 0.114f * B2;
        const bool ok = (unsigned)r < (unsigned)IMG;
        float g0 = eL ? 0.0f : GA.x;                  // col cb-2
        float g1 = eL ? 0.0f : GA.y;                  // col cb-1
        float g2 = eL ? GA.x : GA.z;                  // col cb
        float g3 = eL ? GA.y : GA.w;                  // col cb+1
        float g4 = eR ? GB.z : GB.x;                  // col cb+2
        float g5 = eR ? GB.w : GB.y;                  // col cb+3
        float g6 = eR ? 0.0f : GB.z;                  // col cb+4
        float g7 = eR ? 0.0f : GB.w;                  // col cb+5
        g[0] = ok ? g0 : 0.0f;  g[1] = ok ? g1 : 0.0f;
        g[2] = ok ? g2 : 0.0f;  g[3] = ok ? g3 : 0.0f;
        g[4] = ok ? g4 : 0.0f;  g[5] = ok ? g5 : 0.0f;
        g[6] = ok ? g6 : 0.0f;  g[7] = ok ? g7 : 0.0f;
    };

    // ---- init: gray rows r0-2 (gb), r0-1 (gc); raw prefetch of row r0 ----
    {
        int b = rowbase(r0 - 2);
        mk8(*(const f32x4*)(x0+b+cA), *(const f32x4*)(x1+b+cA), *(const f32x4*)(x2+b+cA),
            *(const f32x4*)(x0+b+cB), *(const f32x4*)(x1+b+cB), *(const f32x4*)(x2+b+cB),
            r0 - 2, gb);
        b = rowbase(r0 - 1);
        mk8(*(const f32x4*)(x0+b+cA), *(const f32x4*)(x1+b+cA), *(const f32x4*)(x2+b+cA),
            *(const f32x4*)(x0+b+cB), *(const f32x4*)(x1+b+cB), *(const f32x4*)(x2+b+cB),
            r0 - 1, gc);
    }
    int pb = rowbase(r0);
    f32x4 pA0 = *(const f32x4*)(x0 + pb + cA);
    f32x4 pA1 = *(const f32x4*)(x1 + pb + cA);
    f32x4 pA2 = *(const f32x4*)(x2 + pb + cA);
    f32x4 pB0 = *(const f32x4*)(x0 + pb + cB);
    f32x4 pB1 = *(const f32x4*)(x1 + pb + cB);
    f32x4 pB2 = *(const f32x4*)(x2 + pb + cB);

    const f32x4 VZERO = {0.f, 0.f, 0.f, 0.f};
    f32x4 hxx1 = VZERO, hyy1 = VZERO, hxy1 = VZERO;   // h sums at edge row e-1
    f32x4 hxx2 = VZERO, hyy2 = VZERO, hxy2 = VZERO;   // h sums at edge row e-2

    #pragma unroll 2
    for (int t = 0; t < H + 2; ++t) {                 // 10 iterations
        const int e = r0 - 1 + t;

        // consume raw row e+1 (issued last iter), issue prefetch of row e+2
        f32x4 rA0 = pA0, rA1 = pA1, rA2 = pA2;
        f32x4 rB0 = pB0, rB1 = pB1, rB2 = pB2;
        int nb = rowbase(e + 2);
        pA0 = *(const f32x4*)(x0 + nb + cA);
        pA1 = *(const f32x4*)(x1 + nb + cA);
        pA2 = *(const f32x4*)(x2 + nb + cA);
        pB0 = *(const f32x4*)(x0 + nb + cB);
        pB1 = *(const f32x4*)(x1 + nb + cB);
        pB2 = *(const f32x4*)(x2 + nb + cB);

        #pragma unroll
        for (int j = 0; j < 8; ++j) { ga[j] = gb[j]; gb[j] = gc[j]; }
        mk8(rA0, rA1, rA2, rB0, rB1, rB2, e + 1, gc);

        float s[8], d[8];
        #pragma unroll
        for (int j = 0; j < 8; ++j) {
            s[j] = (ga[j] + gc[j]) + W103 * gb[j];    // vertical smooth (/3)
            d[j] = gc[j] - ga[j];                     // vertical diff
        }

        const bool ev = (unsigned)e < (unsigned)IMG;
        float ixa[6], iya[6];                         // edge cols cb-1 .. cb+4
        #pragma unroll
        for (int m = 0; m < 6; ++m) {
            float ixv = s[m + 2] - s[m];                        // Ix/3
            float iyv = (d[m] + d[m + 2]) + W103 * d[m + 1];    // Iy/3
            ixa[m] = ev ? ixv : 0.0f;
            iya[m] = ev ? iyv : 0.0f;
        }
        ixa[0] = eL ? 0.0f : ixa[0];  iya[0] = eL ? 0.0f : iya[0];  // col -1
        ixa[5] = eR ? 0.0f : ixa[5];  iya[5] = eR ? 0.0f : iya[5];  // col 4096

        if (t >= 1 && t <= H) {                       // edge mag = 1.5*(|ix'|+|iy'|)
            f32x4 m;
            #pragma unroll
            for (int k = 0; k < 4; ++k)
                m[k] = 1.5f * (fabsf(ixa[k + 1]) + fabsf(iya[k + 1]));
            __builtin_nontemporal_store(m, (f32x4*)(&out_edge[e * IMG + cb]));
        }

        float qxx[6], qyy[6], qxy[6];
        #pragma unroll
        for (int j = 0; j < 6; ++j) {
            qxx[j] = ixa[j] * ixa[j];
            qyy[j] = iya[j] * iya[j];
            qxy[j] = ixa[j] * iya[j];
        }
        f32x4 hxx, hyy, hxy;
        #pragma unroll
        for (int k = 0; k < 4; ++k) {
            hxx[k] = qxx[k] + qxx[k + 1] + qxx[k + 2];
            hyy[k] = qyy[k] + qyy[k + 1] + qyy[k + 2];
            hxy[k] = qxy[k] + qxy[k + 1] + qxy[k + 2];
        }

        if (t >= 2) {                                 // output row o = e-1
            const int o = e - 1;
            f32x4 vv;
            #pragma unroll
            for (int k = 0; k < 4; ++k) {
                float sxx = hxx2[k] + hxx1[k] + hxx[k];
                float syy = hyy2[k] + hyy1[k] + hyy[k];
                float sxy = hxy2[k] + hxy1[k] + hxy[k];
                float diff = sxx - syy;
                float tr   = sxx + syy;
                float t2   = 2.0f * sxy;
                vv[k] = 9.0f * (tr - sqrtf(diff * diff + t2 * t2));
            }
            __builtin_nontemporal_store(vv, (f32x4*)(&out_eig[o * IMG + cb]));
        }
        hxx2 = hxx1; hxx1 = hxx;
        hyy2 = hyy1; hyy1 = hyy;
        hxy2 = hxy1; hxy1 = hxy;
    }
}

extern "C" void kernel_launch(void* const* d_in, const int* in_sizes, int n_in,
                              void* d_out, int out_size, void* d_ws, size_t ws_size,
                              hipStream_t stream) {
    const float* x = (const float*)d_in[0];
    float* out      = (float*)d_out;
    float* out_edge = out;                       // output 0: (1,4096,4096)
    float* out_eig  = out + (size_t)IMG * IMG;   // output 1: (1,4096,4096)

    dim3 grid(4, IMG / H);                       // 4 panel-quads x 512 strips = 2048 blocks
    dim3 block(64, 4);                           // wave = 256 cols; block = 1024 contiguous
    harris_stream8<<<grid, block, 0, stream>>>(x, out_edge, out_eig);
}

// Round 15
// 69.910 us; speedup vs baseline: 1.0497x; 1.0497x over previous
//
#include <hip/hip_runtime.h>

#define IMG  4096
#define H    16              // output rows per wave strip
#define W103 3.33333333333333f   // 10/3 (x3 scharr scale deferred to epilogue)

typedef float f32x4 __attribute__((ext_vector_type(4)));

__global__ __launch_bounds__(256)
void harris_stream8(const float* __restrict__ x,
                    float* __restrict__ out_edge,
                    float* __restrict__ out_eig)
{
    const int lane  = threadIdx.x;                    // 0..63
    const int panel = blockIdx.x * 4 + threadIdx.y;   // 0..15 (256 cols each)
    const int r0    = blockIdx.y * H;
    const int cb    = panel * 256 + lane * 4;         // output col base (mult of 4)
    const bool eL   = (cb == 0);
    const bool eR   = (cb == IMG - 4);
    const int  cA   = eL ? 0 : cb - 2;                // LA: gray cols cA..cA+3 (8B aligned)
    const int  cB   = eR ? cb : cb + 2;               // LB: gray cols cB..cB+3

    const float* __restrict__ x0 = x;
    const float* __restrict__ x1 = x + (size_t)IMG * IMG;
    const float* __restrict__ x2 = x + 2 * (size_t)IMG * IMG;

    auto rowbase = [&](int r) -> int {                // clamped, always-safe row base
        int rc = min(max(r, 0), IMG - 1);
        return rc * IMG;
    };

    float ga[8], gb[8], gc[8];                        // gray ring rows e-1, e, e+1

    // build gray[8] = cols cb-2..cb+5 (edge-adjusted, zero outside image)
    auto mk8 = [&](f32x4 A0, f32x4 A1, f32x4 A2,
                   f32x4 B0, f32x4 B1, f32x4 B2, int r, float* g) {
        f32x4 GA = 0.299f * A0 + 0.587f * A1 + 0.114f * A2;
        f32x4 GB = 0.299f * B0 + 0.587f * B1 + 0.114f * B2;
        const bool ok = (unsigned)r < (unsigned)IMG;
        float g0 = eL ? 0.0f : GA.x;                  // col cb-2
        float g1 = eL ? 0.0f : GA.y;                  // col cb-1
        float g2 = eL ? GA.x : GA.z;                  // col cb
        float g3 = eL ? GA.y : GA.w;                  // col cb+1
        float g4 = eR ? GB.z : GB.x;                  // col cb+2
        float g5 = eR ? GB.w : GB.y;                  // col cb+3
        float g6 = eR ? 0.0f : GB.z;                  // col cb+4
        float g7 = eR ? 0.0f : GB.w;                  // col cb+5
        g[0] = ok ? g0 : 0.0f;  g[1] = ok ? g1 : 0.0f;
        g[2] = ok ? g2 : 0.0f;  g[3] = ok ? g3 : 0.0f;
        g[4] = ok ? g4 : 0.0f;  g[5] = ok ? g5 : 0.0f;
        g[6] = ok ? g6 : 0.0f;  g[7] = ok ? g7 : 0.0f;
    };

    // ---- init: gray rows r0-2 (gb), r0-1 (gc); ping-pong prefetch rows r0 (P), r0+1 (Q) --
    {
        int b = rowbase(r0 - 2);
        mk8(*(const f32x4*)(x0+b+cA), *(const f32x4*)(x1+b+cA), *(const f32x4*)(x2+b+cA),
            *(const f32x4*)(x0+b+cB), *(const f32x4*)(x1+b+cB), *(const f32x4*)(x2+b+cB),
            r0 - 2, gb);
        b = rowbase(r0 - 1);
        mk8(*(const f32x4*)(x0+b+cA), *(const f32x4*)(x1+b+cA), *(const f32x4*)(x2+b+cA),
            *(const f32x4*)(x0+b+cB), *(const f32x4*)(x1+b+cB), *(const f32x4*)(x2+b+cB),
            r0 - 1, gc);
    }
    int pb = rowbase(r0);
    f32x4 PA0 = *(const f32x4*)(x0 + pb + cA);
    f32x4 PA1 = *(const f32x4*)(x1 + pb + cA);
    f32x4 PA2 = *(const f32x4*)(x2 + pb + cA);
    f32x4 PB0 = *(const f32x4*)(x0 + pb + cB);
    f32x4 PB1 = *(const f32x4*)(x1 + pb + cB);
    f32x4 PB2 = *(const f32x4*)(x2 + pb + cB);
    int qb = rowbase(r0 + 1);
    f32x4 QA0 = *(const f32x4*)(x0 + qb + cA);
    f32x4 QA1 = *(const f32x4*)(x1 + qb + cA);
    f32x4 QA2 = *(const f32x4*)(x2 + qb + cA);
    f32x4 QB0 = *(const f32x4*)(x0 + qb + cB);
    f32x4 QB1 = *(const f32x4*)(x1 + qb + cB);
    f32x4 QB2 = *(const f32x4*)(x2 + qb + cB);

    const f32x4 VZERO = {0.f, 0.f, 0.f, 0.f};
    f32x4 hxx1 = VZERO, hyy1 = VZERO, hxy1 = VZERO;   // h sums at edge row e-1
    f32x4 hxx2 = VZERO, hyy2 = VZERO, hxy2 = VZERO;   // h sums at edge row e-2

    // body(t): consume buffer (row e+1 = r0+t, loads issued at t-2), re-issue it for row e+3
    auto body = [&](int t, f32x4& A0, f32x4& A1, f32x4& A2,
                           f32x4& B0, f32x4& B1, f32x4& B2) {
        const int e = r0 - 1 + t;

        f32x4 rA0 = A0, rA1 = A1, rA2 = A2;           // consume (vmcnt wait: 2 iters old)
        f32x4 rB0 = B0, rB1 = B1, rB2 = B2;
        int nb = rowbase(e + 3);                      // re-issue same buffer for row e+3
        A0 = *(const f32x4*)(x0 + nb + cA);
        A1 = *(const f32x4*)(x1 + nb + cA);
        A2 = *(const f32x4*)(x2 + nb + cA);
        B0 = *(const f32x4*)(x0 + nb + cB);
        B1 = *(const f32x4*)(x1 + nb + cB);
        B2 = *(const f32x4*)(x2 + nb + cB);

        #pragma unroll
        for (int j = 0; j < 8; ++j) { ga[j] = gb[j]; gb[j] = gc[j]; }
        mk8(rA0, rA1, rA2, rB0, rB1, rB2, e + 1, gc);

        float s[8], d[8];
        #pragma unroll
        for (int j = 0; j < 8; ++j) {
            s[j] = (ga[j] + gc[j]) + W103 * gb[j];    // vertical smooth (/3)
            d[j] = gc[j] - ga[j];                     // vertical diff
        }

        const bool ev = (unsigned)e < (unsigned)IMG;
        float ixa[6], iya[6];                         // edge cols cb-1 .. cb+4
        #pragma unroll
        for (int m = 0; m < 6; ++m) {
            float ixv = s[m + 2] - s[m];                        // Ix/3
            float iyv = (d[m] + d[m + 2]) + W103 * d[m + 1];    // Iy/3
            ixa[m] = ev ? ixv : 0.0f;
            iya[m] = ev ? iyv : 0.0f;
        }
        ixa[0] = eL ? 0.0f : ixa[0];  iya[0] = eL ? 0.0f : iya[0];  // col -1
        ixa[5] = eR ? 0.0f : ixa[5];  iya[5] = eR ? 0.0f : iya[5];  // col 4096

        if (t >= 1 && t <= H) {                       // edge mag = 1.5*(|ix'|+|iy'|)
            f32x4 m;
            #pragma unroll
            for (int k = 0; k < 4; ++k)
                m[k] = 1.5f * (fabsf(ixa[k + 1]) + fabsf(iya[k + 1]));
            __builtin_nontemporal_store(m, (f32x4*)(&out_edge[e * IMG + cb]));
        }

        float qxx[6], qyy[6], qxy[6];
        #pragma unroll
        for (int j = 0; j < 6; ++j) {
            qxx[j] = ixa[j] * ixa[j];
            qyy[j] = iya[j] * iya[j];
            qxy[j] = ixa[j] * iya[j];
        }
        f32x4 hxx, hyy, hxy;
        #pragma unroll
        for (int k = 0; k < 4; ++k) {
            hxx[k] = qxx[k] + qxx[k + 1] + qxx[k + 2];
            hyy[k] = qyy[k] + qyy[k + 1] + qyy[k + 2];
            hxy[k] = qxy[k] + qxy[k + 1] + qxy[k + 2];
        }

        if (t >= 2) {                                 // output row o = e-1
            const int o = e - 1;
            f32x4 vv;
            #pragma unroll
            for (int k = 0; k < 4; ++k) {
                float sxx = hxx2[k] + hxx1[k] + hxx[k];
                float syy = hyy2[k] + hyy1[k] + hyy[k];
                float sxy = hxy2[k] + hxy1[k] + hxy[k];
                float diff = sxx - syy;
                float tr   = sxx + syy;
                float t2   = 2.0f * sxy;
                vv[k] = 9.0f * (tr - sqrtf(diff * diff + t2 * t2));
            }
            __builtin_nontemporal_store(vv, (f32x4*)(&out_eig[o * IMG + cb]));
        }
        hxx2 = hxx1; hxx1 = hxx;
        hyy2 = hyy1; hyy1 = hyy;
        hxy2 = hxy1; hxy1 = hxy;
    };

    // ---- 18 iterations as 9 static ping-pong pairs (even->P, odd->Q) ----
    #pragma unroll 1
    for (int tt = 0; tt < (H + 2) / 2; ++tt) {
        body(2 * tt,     PA0, PA1, PA2, PB0, PB1, PB2);
        body(2 * tt + 1, QA0, QA1, QA2, QB0, QB1, QB2);
    }
}

extern "C" void kernel_launch(void* const* d_in, const int* in_sizes, int n_in,
                              void* d_out, int out_size, void* d_ws, size_t ws_size,
                              hipStream_t stream) {
    const float* x = (const float*)d_in[0];
    float* out      = (float*)d_out;
    float* out_edge = out;                       // output 0: (1,4096,4096)
    float* out_eig  = out + (size_t)IMG * IMG;   // output 1: (1,4096,4096)

    dim3 grid(4, IMG / H);                       // 4 panel-quads x 256 strips = 1024 blocks
    dim3 block(64, 4);                           // wave = 256 cols; block = 1024 contiguous
    harris_stream8<<<grid, block, 0, stream>>>(x, out_edge, out_eig);
}

// Round 16
// 63.022 us; speedup vs baseline: 1.1644x; 1.1093x over previous
//
#include <hip/hip_runtime.h>

#define IMG  4096
#define H    16              // output rows per wave strip
#define W103 3.33333333333333f   // 10/3 (x3 scharr scale deferred to epilogue)

typedef float f32x4 __attribute__((ext_vector_type(4)));

__global__ __launch_bounds__(256)
void harris_stream8(const float* __restrict__ x,
                    float* __restrict__ out_edge,
                    float* __restrict__ out_eig)
{
    const int lane  = threadIdx.x;                    // 0..63
    // ---- XCD-chunked swizzle: give each XCD 32 contiguous strips ----
    // id = hw linear block id (4 x 256 grid); xcd ~= id % 8 (round-robin dispatch).
    // w = (id%8)*128 + id/8 is bijective on [0,1024); XCD x then owns w in
    // [128x,128x+128) = strips [32x, 32x+32) -> vertical halos are same-L2.
    const int id  = blockIdx.x + 4 * blockIdx.y;
    const int w   = (id & 7) * 128 + (id >> 3);
    const int pq  = w & 3;                            // panel quad 0..3
    const int sy  = w >> 2;                           // strip 0..255
    const int panel = pq * 4 + threadIdx.y;           // 0..15 (256 cols each)
    const int r0    = sy * H;
    const int cb    = panel * 256 + lane * 4;         // output col base (mult of 4)
    const bool eL   = (cb == 0);
    const bool eR   = (cb == IMG - 4);
    const int  cA   = eL ? 0 : cb - 2;                // LA: gray cols cA..cA+3 (8B aligned)
    const int  cB   = eR ? cb : cb + 2;               // LB: gray cols cB..cB+3

    const float* __restrict__ x0 = x;
    const float* __restrict__ x1 = x + (size_t)IMG * IMG;
    const float* __restrict__ x2 = x + 2 * (size_t)IMG * IMG;

    auto rowbase = [&](int r) -> int {                // clamped, always-safe row base
        int rc = min(max(r, 0), IMG - 1);
        return rc * IMG;
    };

    float ga[8], gb[8], gc[8];                        // gray ring rows e-1, e, e+1

    // build gray[8] = cols cb-2..cb+5 (edge-adjusted, zero outside image)
    auto mk8 = [&](f32x4 A0, f32x4 A1, f32x4 A2,
                   f32x4 B0, f32x4 B1, f32x4 B2, int r, float* g) {
        f32x4 GA = 0.299f * A0 + 0.587f * A1 + 0.114f * A2;
        f32x4 GB = 0.299f * B0 + 0.587f * B1 + 0.114f * B2;
        const bool ok = (unsigned)r < (unsigned)IMG;
        float g0 = eL ? 0.0f : GA.x;                  // col cb-2
        float g1 = eL ? 0.0f : GA.y;                  // col cb-1
        float g2 = eL ? GA.x : GA.z;                  // col cb
        float g3 = eL ? GA.y : GA.w;                  // col cb+1
        float g4 = eR ? GB.z : GB.x;                  // col cb+2
        float g5 = eR ? GB.w : GB.y;                  // col cb+3
        float g6 = eR ? 0.0f : GB.z;                  // col cb+4
        float g7 = eR ? 0.0f : GB.w;                  // col cb+5
        g[0] = ok ? g0 : 0.0f;  g[1] = ok ? g1 : 0.0f;
        g[2] = ok ? g2 : 0.0f;  g[3] = ok ? g3 : 0.0f;
        g[4] = ok ? g4 : 0.0f;  g[5] = ok ? g5 : 0.0f;
        g[6] = ok ? g6 : 0.0f;  g[7] = ok ? g7 : 0.0f;
    };

    // ---- init: gray rows r0-2 (gb), r0-1 (gc); raw prefetch of row r0 ----
    {
        int b = rowbase(r0 - 2);
        mk8(*(const f32x4*)(x0+b+cA), *(const f32x4*)(x1+b+cA), *(const f32x4*)(x2+b+cA),
            *(const f32x4*)(x0+b+cB), *(const f32x4*)(x1+b+cB), *(const f32x4*)(x2+b+cB),
            r0 - 2, gb);
        b = rowbase(r0 - 1);
        mk8(*(const f32x4*)(x0+b+cA), *(const f32x4*)(x1+b+cA), *(const f32x4*)(x2+b+cA),
            *(const f32x4*)(x0+b+cB), *(const f32x4*)(x1+b+cB), *(const f32x4*)(x2+b+cB),
            r0 - 1, gc);
    }
    int pb = rowbase(r0);
    f32x4 pA0 = *(const f32x4*)(x0 + pb + cA);
    f32x4 pA1 = *(const f32x4*)(x1 + pb + cA);
    f32x4 pA2 = *(const f32x4*)(x2 + pb + cA);
    f32x4 pB0 = *(const f32x4*)(x0 + pb + cB);
    f32x4 pB1 = *(const f32x4*)(x1 + pb + cB);
    f32x4 pB2 = *(const f32x4*)(x2 + pb + cB);

    const f32x4 VZERO = {0.f, 0.f, 0.f, 0.f};
    f32x4 hxx1 = VZERO, hyy1 = VZERO, hxy1 = VZERO;   // h sums at edge row e-1
    f32x4 hxx2 = VZERO, hyy2 = VZERO, hxy2 = VZERO;   // h sums at edge row e-2

    #pragma unroll 3
    for (int t = 0; t < H + 2; ++t) {                 // 18 iterations (3 | 18)
        const int e = r0 - 1 + t;

        // consume raw row e+1 (issued last iter), issue prefetch of row e+2
        f32x4 rA0 = pA0, rA1 = pA1, rA2 = pA2;
        f32x4 rB0 = pB0, rB1 = pB1, rB2 = pB2;
        int nb = rowbase(e + 2);
        pA0 = *(const f32x4*)(x0 + nb + cA);
        pA1 = *(const f32x4*)(x1 + nb + cA);
        pA2 = *(const f32x4*)(x2 + nb + cA);
        pB0 = *(const f32x4*)(x0 + nb + cB);
        pB1 = *(const f32x4*)(x1 + nb + cB);
        pB2 = *(const f32x4*)(x2 + nb + cB);

        #pragma unroll
        for (int j = 0; j < 8; ++j) { ga[j] = gb[j]; gb[j] = gc[j]; }
        mk8(rA0, rA1, rA2, rB0, rB1, rB2, e + 1, gc);

        float s[8], d[8];
        #pragma unroll
        for (int j = 0; j < 8; ++j) {
            s[j] = (ga[j] + gc[j]) + W103 * gb[j];    // vertical smooth (/3)
            d[j] = gc[j] - ga[j];                     // vertical diff
        }

        const bool ev = (unsigned)e < (unsigned)IMG;
        float ixa[6], iya[6];                         // edge cols cb-1 .. cb+4
        #pragma unroll
        for (int m = 0; m < 6; ++m) {
            float ixv = s[m + 2] - s[m];                        // Ix/3
            float iyv = (d[m] + d[m + 2]) + W103 * d[m + 1];    // Iy/3
            ixa[m] = ev ? ixv : 0.0f;
            iya[m] = ev ? iyv : 0.0f;
        }
        ixa[0] = eL ? 0.0f : ixa[0];  iya[0] = eL ? 0.0f : iya[0];  // col -1
        ixa[5] = eR ? 0.0f : ixa[5];  iya[5] = eR ? 0.0f : iya[5];  // col 4096

        if (t >= 1 && t <= H) {                       // edge mag = 1.5*(|ix'|+|iy'|)
            f32x4 m;
            #pragma unroll
            for (int k = 0; k < 4; ++k)
                m[k] = 1.5f * (fabsf(ixa[k + 1]) + fabsf(iya[k + 1]));
            __builtin_nontemporal_store(m, (f32x4*)(&out_edge[e * IMG + cb]));
        }

        float qxx[6], qyy[6], qxy[6];
        #pragma unroll
        for (int j = 0; j < 6; ++j) {
            qxx[j] = ixa[j] * ixa[j];
            qyy[j] = iya[j] * iya[j];
            qxy[j] = ixa[j] * iya[j];
        }
        f32x4 hxx, hyy, hxy;
        #pragma unroll
        for (int k = 0; k < 4; ++k) {
            hxx[k] = qxx[k] + qxx[k + 1] + qxx[k + 2];
            hyy[k] = qyy[k] + qyy[k + 1] + qyy[k + 2];
            hxy[k] = qxy[k] + qxy[k + 1] + qxy[k + 2];
        }

        if (t >= 2) {                                 // output row o = e-1
            const int o = e - 1;
            f32x4 vv;
            #pragma unroll
            for (int k = 0; k < 4; ++k) {
                float sxx = hxx2[k] + hxx1[k] + hxx[k];
                float syy = hyy2[k] + hyy1[k] + hyy[k];
                float sxy = hxy2[k] + hxy1[k] + hxy[k];
                float diff = sxx - syy;
                float tr   = sxx + syy;
                float t2   = 2.0f * sxy;
                vv[k] = 9.0f * (tr - sqrtf(diff * diff + t2 * t2));
            }
            __builtin_nontemporal_store(vv, (f32x4*)(&out_eig[o * IMG + cb]));
        }
        hxx2 = hxx1; hxx1 = hxx;
        hyy2 = hyy1; hyy1 = hyy;
        hxy2 = hxy1; hxy1 = hxy;
    }
}

extern "C" void kernel_launch(void* const* d_in, const int* in_sizes, int n_in,
                              void* d_out, int out_size, void* d_ws, size_t ws_size,
                              hipStream_t stream) {
    const float* x = (const float*)d_in[0];
    float* out      = (float*)d_out;
    float* out_edge = out;                       // output 0: (1,4096,4096)
    float* out_eig  = out + (size_t)IMG * IMG;   // output 1: (1,4096,4096)

    dim3 grid(4, IMG / H);                       // 4 panel-quads x 256 strips = 1024 blocks
    dim3 block(64, 4);                           // wave = 256 cols; block = 1024 contiguous
    harris_stream8<<<grid, block, 0, stream>>>(x, out_edge, out_eig);
}

// Round 17
// 57.822 us; speedup vs baseline: 1.2691x; 1.0899x over previous
//
#include <hip/hip_runtime.h>

#define IMG  4096
#define H    32              // output rows per wave strip
#define W103 3.33333333333333f   // 10/3 (x3 scharr scale deferred to epilogue)

typedef float f32x4 __attribute__((ext_vector_type(4)));

__global__ __launch_bounds__(256)
void harris_stream8(const float* __restrict__ x,
                    float* __restrict__ out_edge,
                    float* __restrict__ out_eig)
{
    const int lane  = threadIdx.x;                    // 0..63
    // ---- XCD-chunked swizzle: 512 blocks, 64 contiguous per XCD ----
    // id = hw linear block id; xcd ~= id % 8. w = (id%8)*64 + id/8 bijective on [0,512);
    // XCD x owns w in [64x,64x+64) -> strips [16x,16x+16) -> rows [512x,512x+512).
    const int id  = blockIdx.x + 4 * blockIdx.y;
    const int w   = (id & 7) * 64 + (id >> 3);
    const int pq  = w & 3;                            // panel quad 0..3
    const int sy  = w >> 2;                           // strip 0..127
    const int panel = pq * 4 + threadIdx.y;           // 0..15 (256 cols each)
    const int r0    = sy * H;
    const int cb    = panel * 256 + lane * 4;         // output col base (mult of 4)
    const bool eL   = (cb == 0);
    const bool eR   = (cb == IMG - 4);
    const int  cA   = eL ? 0 : cb - 2;                // LA: gray cols cA..cA+3 (8B aligned)
    const int  cB   = eR ? cb : cb + 2;               // LB: gray cols cB..cB+3

    const float* __restrict__ x0 = x;
    const float* __restrict__ x1 = x + (size_t)IMG * IMG;
    const float* __restrict__ x2 = x + 2 * (size_t)IMG * IMG;

    auto rowbase = [&](int r) -> int {                // clamped, always-safe row base
        int rc = min(max(r, 0), IMG - 1);
        return rc * IMG;
    };

    float ga[8], gb[8], gc[8];                        // gray ring rows e-1, e, e+1

    // build gray[8] = cols cb-2..cb+5 (edge-adjusted, zero outside image)
    auto mk8 = [&](f32x4 A0, f32x4 A1, f32x4 A2,
                   f32x4 B0, f32x4 B1, f32x4 B2, int r, float* g) {
        f32x4 GA = 0.299f * A0 + 0.587f * A1 + 0.114f * A2;
        f32x4 GB = 0.299f * B0 + 0.587f * B1 + 0.114f * B2;
        const bool ok = (unsigned)r < (unsigned)IMG;
        float g0 = eL ? 0.0f : GA.x;                  // col cb-2
        float g1 = eL ? 0.0f : GA.y;                  // col cb-1
        float g2 = eL ? GA.x : GA.z;                  // col cb
        float g3 = eL ? GA.y : GA.w;                  // col cb+1
        float g4 = eR ? GB.z : GB.x;                  // col cb+2
        float g5 = eR ? GB.w : GB.y;                  // col cb+3
        float g6 = eR ? 0.0f : GB.z;                  // col cb+4
        float g7 = eR ? 0.0f : GB.w;                  // col cb+5
        g[0] = ok ? g0 : 0.0f;  g[1] = ok ? g1 : 0.0f;
        g[2] = ok ? g2 : 0.0f;  g[3] = ok ? g3 : 0.0f;
        g[4] = ok ? g4 : 0.0f;  g[5] = ok ? g5 : 0.0f;
        g[6] = ok ? g6 : 0.0f;  g[7] = ok ? g7 : 0.0f;
    };

    // ---- init: gray rows r0-2 (gb), r0-1 (gc); raw prefetch of row r0 ----
    {
        int b = rowbase(r0 - 2);
        mk8(*(const f32x4*)(x0+b+cA), *(const f32x4*)(x1+b+cA), *(const f32x4*)(x2+b+cA),
            *(const f32x4*)(x0+b+cB), *(const f32x4*)(x1+b+cB), *(const f32x4*)(x2+b+cB),
            r0 - 2, gb);
        b = rowbase(r0 - 1);
        mk8(*(const f32x4*)(x0+b+cA), *(const f32x4*)(x1+b+cA), *(const f32x4*)(x2+b+cA),
            *(const f32x4*)(x0+b+cB), *(const f32x4*)(x1+b+cB), *(const f32x4*)(x2+b+cB),
            r0 - 1, gc);
    }
    int pb = rowbase(r0);
    f32x4 pA0 = *(const f32x4*)(x0 + pb + cA);
    f32x4 pA1 = *(const f32x4*)(x1 + pb + cA);
    f32x4 pA2 = *(const f32x4*)(x2 + pb + cA);
    f32x4 pB0 = *(const f32x4*)(x0 + pb + cB);
    f32x4 pB1 = *(const f32x4*)(x1 + pb + cB);
    f32x4 pB2 = *(const f32x4*)(x2 + pb + cB);

    const f32x4 VZERO = {0.f, 0.f, 0.f, 0.f};
    f32x4 hxx1 = VZERO, hyy1 = VZERO, hxy1 = VZERO;   // h sums at edge row e-1
    f32x4 hxx2 = VZERO, hyy2 = VZERO, hxy2 = VZERO;   // h sums at edge row e-2

    #pragma unroll 2
    for (int t = 0; t < H + 2; ++t) {                 // 34 iterations (2 | 34)
        const int e = r0 - 1 + t;

        // consume raw row e+1 (issued last iter), issue prefetch of row e+2
        f32x4 rA0 = pA0, rA1 = pA1, rA2 = pA2;
        f32x4 rB0 = pB0, rB1 = pB1, rB2 = pB2;
        int nb = rowbase(e + 2);
        pA0 = *(const f32x4*)(x0 + nb + cA);
        pA1 = *(const f32x4*)(x1 + nb + cA);
        pA2 = *(const f32x4*)(x2 + nb + cA);
        pB0 = *(const f32x4*)(x0 + nb + cB);
        pB1 = *(const f32x4*)(x1 + nb + cB);
        pB2 = *(const f32x4*)(x2 + nb + cB);

        #pragma unroll
        for (int j = 0; j < 8; ++j) { ga[j] = gb[j]; gb[j] = gc[j]; }
        mk8(rA0, rA1, rA2, rB0, rB1, rB2, e + 1, gc);

        float s[8], d[8];
        #pragma unroll
        for (int j = 0; j < 8; ++j) {
            s[j] = (ga[j] + gc[j]) + W103 * gb[j];    // vertical smooth (/3)
            d[j] = gc[j] - ga[j];                     // vertical diff
        }

        const bool ev = (unsigned)e < (unsigned)IMG;
        float ixa[6], iya[6];                         // edge cols cb-1 .. cb+4
        #pragma unroll
        for (int m = 0; m < 6; ++m) {
            float ixv = s[m + 2] - s[m];                        // Ix/3
            float iyv = (d[m] + d[m + 2]) + W103 * d[m + 1];    // Iy/3
            ixa[m] = ev ? ixv : 0.0f;
            iya[m] = ev ? iyv : 0.0f;
        }
        ixa[0] = eL ? 0.0f : ixa[0];  iya[0] = eL ? 0.0f : iya[0];  // col -1
        ixa[5] = eR ? 0.0f : ixa[5];  iya[5] = eR ? 0.0f : iya[5];  // col 4096

        if (t >= 1 && t <= H) {                       // edge mag = 1.5*(|ix'|+|iy'|)
            f32x4 m;
            #pragma unroll
            for (int k = 0; k < 4; ++k)
                m[k] = 1.5f * (fabsf(ixa[k + 1]) + fabsf(iya[k + 1]));
            __builtin_nontemporal_store(m, (f32x4*)(&out_edge[e * IMG + cb]));
        }

        float qxx[6], qyy[6], qxy[6];
        #pragma unroll
        for (int j = 0; j < 6; ++j) {
            qxx[j] = ixa[j] * ixa[j];
            qyy[j] = iya[j] * iya[j];
            qxy[j] = ixa[j] * iya[j];
        }
        f32x4 hxx, hyy, hxy;
        #pragma unroll
        for (int k = 0; k < 4; ++k) {
            hxx[k] = qxx[k] + qxx[k + 1] + qxx[k + 2];
            hyy[k] = qyy[k] + qyy[k + 1] + qyy[k + 2];
            hxy[k] = qxy[k] + qxy[k + 1] + qxy[k + 2];
        }

        if (t >= 2) {                                 // output row o = e-1
            const int o = e - 1;
            f32x4 vv;
            #pragma unroll
            for (int k = 0; k < 4; ++k) {
                float sxx = hxx2[k] + hxx1[k] + hxx[k];
                float syy = hyy2[k] + hyy1[k] + hyy[k];
                float sxy = hxy2[k] + hxy1[k] + hxy[k];
                float diff = sxx - syy;
                float tr   = sxx + syy;
                float t2   = 2.0f * sxy;
                vv[k] = 9.0f * (tr - sqrtf(diff * diff + t2 * t2));
            }
            __builtin_nontemporal_store(vv, (f32x4*)(&out_eig[o * IMG + cb]));
        }
        hxx2 = hxx1; hxx1 = hxx;
        hyy2 = hyy1; hyy1 = hyy;
        hxy2 = hxy1; hxy1 = hxy;
    }
}

extern "C" void kernel_launch(void* const* d_in, const int* in_sizes, int n_in,
                              void* d_out, int out_size, void* d_ws, size_t ws_size,
                              hipStream_t stream) {
    const float* x = (const float*)d_in[0];
    float* out      = (float*)d_out;
    float* out_edge = out;                       // output 0: (1,4096,4096)
    float* out_eig  = out + (size_t)IMG * IMG;   // output 1: (1,4096,4096)

    dim3 grid(4, IMG / H);                       // 4 panel-quads x 128 strips = 512 blocks
    dim3 block(64, 4);                           // wave = 256 cols; block = 1024 contiguous
    harris_stream8<<<grid, block, 0, stream>>>(x, out_edge, out_eig);
}